// Round 5
// baseline (1169.873 us; speedup 1.0000x reference)
//
#include <hip/hip_runtime.h>
#include <hip/hip_bf16.h>
#include <hip/hip_fp16.h>
#include <stdint.h>

// ComplexAttention: B=4,H=8,T=2048,D=256
// R5: R4's verified 2-phase template at an occupancy-doubling parameter
//     point: BM=BN=128, BK=64, 512 thr (8 waves = 4M x 2N, 32x64/wave),
//     LDS 64 KB -> 2 blocks/CU. Same asm-free STAGE(next)->COMPUTE(cur)
//     ->__syncthreads loop, same pre-swizzled-global-source LDS swizzle
//     (0 conflicts measured in R4), same repack epilogue math (128B row
//     stride), XCD swizzle kept.

#define TSEQ   2048
#define NHEADS 32
#define MTOT   65536   // 32*2048
#define DDC    512
#define HCHUNK 8

typedef float    f32x4  __attribute__((ext_vector_type(4)));
typedef _Float16 f16x8  __attribute__((ext_vector_type(8)));
typedef uint16_t u16x4  __attribute__((ext_vector_type(4)));
typedef uint16_t u16x8  __attribute__((ext_vector_type(8)));

__device__ __forceinline__ uint16_t f2h(float f) {
  _Float16 h = (_Float16)f;
  return __builtin_bit_cast(uint16_t, h);
}
__device__ __forceinline__ float h2f(uint16_t u) {
  return (float)__builtin_bit_cast(_Float16, u);
}

__device__ __forceinline__ void gld16(const void* g, void* l) {
  __builtin_amdgcn_global_load_lds(
      (const __attribute__((address_space(1))) uint32_t*)g,
      (__attribute__((address_space(3))) uint32_t*)l, 16, 0, 0);
}

enum { EP_F16Z = 0, EP_PROJ = 1, EP_OUT = 2, EP_GATE = 3 };

// C[M,N] = A[M,K] * B[N,K]^T  (A,B fp16; accum fp32)
// 512 thr = 8 waves (4M x 2N); tile 128x128; BK=64; per-wave output 32x64.
// LDS: 2 buffers x (A[128][64] + B[128][64]) fp16 = 64 KiB -> 2 blocks/CU.
// Swizzle: LDS physical 16B-chunk p at row r holds global chunk p ^ (r&7);
// staging pre-swizzles the GLOBAL source column (dest stays linear for
// global_load_lds), reads XOR the same key (row mod 8 == fr mod 8 always).
template <int EP>
__global__ __launch_bounds__(512, 4) void gemm_bt(
    const uint16_t* __restrict__ A, int lda, long zA,
    const uint16_t* __restrict__ B, int ldb, long zB,
    void* __restrict__ C, int ldc, long zC, int K,
    const float* __restrict__ biasR, const float* __restrict__ biasI,
    float scale, float* __restrict__ outR, float* __restrict__ outI) {
  constexpr int ABUFE = 128 * 64;        // A elems per buffer (16 KB)
  constexpr int BUFE  = 2 * ABUFE;       // A+B elems per buffer (32 KB)
  __shared__ uint16_t lds[2 * BUFE];     // 64 KiB

  const int tid  = threadIdx.x;
  const int wave = tid >> 6;             // 0..7
  const int lane = tid & 63;
  const int wr   = (wave >> 1) * 32;     // 4 M-warps, 32 rows each
  const int wc   = (wave & 1) * 64;      // 2 N-warps, 64 cols each

  // ---- XCD-aware swizzle (T1): all grids pow2 dims, nwg % 8 == 0.
  const int gx = gridDim.x, gy = gridDim.y;
  const int nwg = gx * gy * gridDim.z;
  const int lin = blockIdx.x + gx * (blockIdx.y + gy * blockIdx.z);
  const int cpx = nwg >> 3;
  const int swz = (lin & 7) * cpx + (lin >> 3);
  const int shx = __popc(gx - 1);
  const int shy = __popc(gy - 1);
  const int bx = swz & (gx - 1);
  const int by = (swz >> shx) & (gy - 1);
  const int bz = swz >> (shx + shy);

  const long tm = (long)by * 128;
  const long tn = (long)bx * 128;
  const uint16_t* Ab = A + (long)bz * zA;
  const uint16_t* Bb = B + (long)bz * zB;

  f32x4 acc[2][4] = {};  // MI=2 row-tiles x NJ=4 col-tiles of 16x16

  // staging: one wave-instruction covers 8 rows x 64 cols (1 KB):
  //   HW dest = base + lane*16 -> row = lane>>3, physical chunk = lane&7.
  //   Global source chunk = (lane&7) ^ (lane>>3)  (the pre-swizzle).
  const int arow   = wave * 8 + (lane >> 3);   // row within a 64-row slab
  const int schunk = (lane & 7) ^ (lane >> 3); // pre-swizzled source chunk

  const int fr   = lane & 15;   // m/n index within mfma tile
  const int quad = lane >> 4;   // 16B k-chunk within the 32-col half
  const int sw   = fr & 7;      // row&7 of every fragment row this lane reads
  const int ch0  = ((0 + quad) ^ sw) * 16;  // byte offset, ks=0
  const int ch1  = ((4 + quad) ^ sw) * 16;  // byte offset, ks=1

  const int nt = K >> 6;  // BK = 64

  auto STAGE = [&](int buf, int t) {
    const long k0 = (long)t * 64 + schunk * 8;
    uint16_t* base = lds + buf * BUFE;
#pragma unroll
    for (int s = 0; s < 2; ++s)
      gld16(Ab + (tm + s * 64 + arow) * (long)lda + k0,
            base + (s * 64 + wave * 8) * 64);
#pragma unroll
    for (int s = 0; s < 2; ++s)
      gld16(Bb + (tn + s * 64 + arow) * (long)ldb + k0,
            base + ABUFE + (s * 64 + wave * 8) * 64);
  };

  auto COMPUTE = [&](int buf) {
    const char* Abase = (const char*)(lds + buf * BUFE);
    const char* Bbase = Abase + 2 * ABUFE;  // ABUFE elems = 2*ABUFE bytes
#pragma unroll
    for (int ks = 0; ks < 2; ++ks) {
      const int co = ks ? ch1 : ch0;
      f16x8 bf[4];
#pragma unroll
      for (int j = 0; j < 4; ++j)
        bf[j] = *(const f16x8*)(Bbase + (wc + j * 16 + fr) * 128 + co);
#pragma unroll
      for (int i = 0; i < 2; ++i) {
        const f16x8 af = *(const f16x8*)(Abase + (wr + i * 16 + fr) * 128 + co);
#pragma unroll
        for (int j = 0; j < 4; ++j)
          acc[i][j] = __builtin_amdgcn_mfma_f32_16x16x32_f16(af, bf[j], acc[i][j], 0, 0, 0);
      }
    }
  };

  // 2-phase pipeline, __syncthreads only (drains vmcnt AFTER compute overlap)
  STAGE(0, 0);
  __syncthreads();
  int cur = 0;
  for (int t = 0; t + 1 < nt; ++t) {
    STAGE(cur ^ 1, t + 1);   // next tile's loads fly during COMPUTE
    COMPUTE(cur);
    __syncthreads();         // publish next tile + guard buffer reuse
    cur ^= 1;
  }
  COMPUTE(cur);              // last tile

  // ---- epilogues ----
  if constexpr (EP == EP_F16Z || EP == EP_PROJ) {
    // LDS repack: per-wave 32x64 fp16 region (4 KB), XOR bits5-6 by
    // (row>>2)&3 -> conflict-free b16 writes and clean b128 reads (same
    // pattern as R4, measured 0 conflicts); then 16B coalesced stores.
    __syncthreads();  // other waves may still be reading the last tile
    char* wbase = (char*)lds + wave * 4096;
    uint16_t* Cp = (uint16_t*)C + ((EP == EP_F16Z) ? (long)bz * zC : 0L);
#pragma unroll
    for (int i = 0; i < 2; ++i) {
#pragma unroll
      for (int j = 0; j < 4; ++j) {
#pragma unroll
        for (int r = 0; r < 4; ++r) {
          const int row = i * 16 + quad * 4 + r;   // 0..31
          int byte = row * 128 + (j * 16 + fr) * 2;
          byte ^= ((row >> 2) & 3) << 5;
          float v = acc[i][j][r];
          if constexpr (EP == EP_PROJ) {
            const int col = (int)tn + wc + j * 16 + fr;
            v += (col < 256) ? biasR[col] : biasI[col - 256];
          } else {
            v *= scale;
          }
          *(uint16_t*)(wbase + byte) = f2h(v);
        }
      }
    }
    asm volatile("s_waitcnt lgkmcnt(0)" ::: "memory");
    __builtin_amdgcn_sched_barrier(0);
#pragma unroll
    for (int it = 0; it < 4; ++it) {
      const int row = it * 8 + (lane >> 3);        // 0..31
      const int c   = lane & 7;
      int byte = row * 128 + c * 16;
      byte ^= ((row >> 2) & 3) << 5;
      const u16x8 val = *(const u16x8*)(wbase + byte);
      const long grow = tm + wr + row;
      const int  gcol = (int)tn + wc + c * 8;
      *(u16x8*)(Cp + grow * (long)ldc + gcol) = val;
    }
  } else {
    // fp32 outputs: 16 lanes x 4B = 64B segments; direct store.
#pragma unroll
    for (int i = 0; i < 2; ++i) {
      const long row0 = tm + wr + i * 16 + quad * 4;
#pragma unroll
      for (int j = 0; j < 4; ++j) {
        const int col = (int)tn + wc + j * 16 + fr;
#pragma unroll
        for (int r = 0; r < 4; ++r) {
          float v = acc[i][j][r];
          const long rw = row0 + r;
          if constexpr (EP == EP_OUT) {
            if (col < 256) outR[rw * 256 + col]       = v + biasR[col];
            else           outI[rw * 256 + col - 256] = v + biasI[col - 256];
          } else {  // EP_GATE
            const float g = 1.0f / (1.0f + __expf(-(v + biasR[col])));
            const long o = rw * 256 + col;
            outR[o] *= g;
            outI[o] *= g;
          }
        }
      }
    }
  }
}

// x fp32 (r,i halves of 256) -> fp16 [m][512]
__global__ void pack_x(const float* __restrict__ xr, const float* __restrict__ xi,
                       uint16_t* __restrict__ out) {
  const long idx = (long)blockIdx.x * 256 + threadIdx.x;  // 4 elems each
  const long m  = idx >> 7;
  const int  c4 = (int)(idx & 127) << 2;
  const float* src = (c4 < 256) ? (xr + m * 256 + c4) : (xi + m * 256 + (c4 - 256));
  const float4 v = *(const float4*)src;
  u16x4 o = {f2h(v.x), f2h(v.y), f2h(v.z), f2h(v.w)};
  *(u16x4*)(out + m * 512 + c4) = o;
}

// Wc[512][512] = [[wr, -wi], [wi, wr]] fp16
__global__ void pack_w(const float* __restrict__ wr, const float* __restrict__ wi,
                       uint16_t* __restrict__ out) {
  const int idx = blockIdx.x * 256 + threadIdx.x;
  const int j  = idx >> 7;
  const int c4 = (idx & 127) << 2;
  const float* src;
  float sgn = 1.f;
  if (j < 256) {
    if (c4 < 256) src = wr + j * 256 + c4;
    else { src = wi + j * 256 + (c4 - 256); sgn = -1.f; }
  } else {
    if (c4 < 256) src = wi + (j - 256) * 256 + c4;
    else          src = wr + (j - 256) * 256 + (c4 - 256);
  }
  const float4 v = *(const float4*)src;
  u16x4 o = {f2h(sgn * v.x), f2h(sgn * v.y), f2h(sgn * v.z), f2h(sgn * v.w)};
  *(u16x4*)(out + (long)j * 512 + c4) = o;
}

__global__ void pack_gw(const float* __restrict__ w, uint16_t* __restrict__ out) {
  const int idx = blockIdx.x * 256 + threadIdx.x;
  const float4 v = *(const float4*)(w + (long)idx * 4);
  u16x4 o = {f2h(v.x), f2h(v.y), f2h(v.z), f2h(v.w)};
  *(u16x4*)(out + (long)idx * 4) = o;
}

// per head: V[2048][512] -> Vt[512][2048]
__global__ void transpose_v(const uint16_t* __restrict__ V, uint16_t* __restrict__ Vt) {
  __shared__ uint16_t t[32][33];
  const int h = blockIdx.z;
  const uint16_t* Vh = V + (long)h * TSEQ * DDC;
  uint16_t* Vth = Vt + (long)h * DDC * TSEQ;
  const int t0 = blockIdx.x * 32;
  const int n0 = blockIdx.y * 32;
  const int lx = threadIdx.x & 31, ly = threadIdx.x >> 5;  // 32x8
#pragma unroll
  for (int yy = ly; yy < 32; yy += 8)
    t[yy][lx] = Vh[(long)(t0 + yy) * DDC + n0 + lx];
  __syncthreads();
#pragma unroll
  for (int yy = ly; yy < 32; yy += 8)
    Vth[(long)(n0 + yy) * TSEQ + t0 + lx] = t[lx][yy];
}

// one block per score row: 2048 fp16 in, softmax, fp16 out (in place)
__global__ __launch_bounds__(256) void softmax_rows(uint16_t* __restrict__ S) {
  const long row = blockIdx.x;
  uint16_t* p = S + row * 2048;
  const int tid = threadIdx.x;
  u16x8 raw = ((const u16x8*)p)[tid];
  float v[8];
#pragma unroll
  for (int j = 0; j < 8; ++j) v[j] = h2f(raw[j]);
  float m = v[0];
#pragma unroll
  for (int j = 1; j < 8; ++j) m = fmaxf(m, v[j]);
#pragma unroll
  for (int off = 32; off >= 1; off >>= 1) m = fmaxf(m, __shfl_xor(m, off));
  __shared__ float red[8];
  const int wave = tid >> 6, lane = tid & 63;
  if (lane == 0) red[wave] = m;
  __syncthreads();
  m = fmaxf(fmaxf(red[0], red[1]), fmaxf(red[2], red[3]));
  float s = 0.f;
#pragma unroll
  for (int j = 0; j < 8; ++j) { v[j] = __expf(v[j] - m); s += v[j]; }
#pragma unroll
  for (int off = 32; off >= 1; off >>= 1) s += __shfl_xor(s, off);
  if (lane == 0) red[4 + wave] = s;
  __syncthreads();
  s = red[4] + red[5] + red[6] + red[7];
  const float inv = 1.0f / s;
  u16x8 o;
#pragma unroll
  for (int j = 0; j < 8; ++j) o[j] = f2h(v[j] * inv);
  ((u16x8*)p)[tid] = o;
}

__global__ void mag_kernel(const float* __restrict__ R, const float* __restrict__ I,
                           uint16_t* __restrict__ mag) {
  const long i = ((long)blockIdx.x * 256 + threadIdx.x) * 4;
  const float4 r  = *(const float4*)(R + i);
  const float4 im = *(const float4*)(I + i);
  u16x4 o = {f2h(sqrtf(r.x * r.x + im.x * im.x + 1e-8f)),
             f2h(sqrtf(r.y * r.y + im.y * im.y + 1e-8f)),
             f2h(sqrtf(r.z * r.z + im.z * im.z + 1e-8f)),
             f2h(sqrtf(r.w * r.w + im.w * im.w + 1e-8f))};
  *(u16x4*)(mag + i) = o;
}

extern "C" void kernel_launch(void* const* d_in, const int* in_sizes, int n_in,
                              void* d_out, int out_size, void* d_ws, size_t ws_size,
                              hipStream_t stream) {
  const float* q_in_r  = (const float*)d_in[0];
  const float* q_in_i  = (const float*)d_in[1];
  const float* kv_in_r = (const float*)d_in[2];
  const float* kv_in_i = (const float*)d_in[3];
  const float* q_wr = (const float*)d_in[4];
  const float* q_wi = (const float*)d_in[5];
  const float* q_br = (const float*)d_in[6];
  const float* q_bi = (const float*)d_in[7];
  const float* k_wr = (const float*)d_in[8];
  const float* k_wi = (const float*)d_in[9];
  const float* k_br = (const float*)d_in[10];
  const float* k_bi = (const float*)d_in[11];
  const float* v_wr = (const float*)d_in[12];
  const float* v_wi = (const float*)d_in[13];
  const float* v_br = (const float*)d_in[14];
  const float* v_bi = (const float*)d_in[15];
  const float* o_wr = (const float*)d_in[16];
  const float* o_wi = (const float*)d_in[17];
  const float* o_br = (const float*)d_in[18];
  const float* o_bi = (const float*)d_in[19];
  const float* gate_w = (const float*)d_in[20];
  const float* gate_b = (const float*)d_in[21];

  // ---- workspace layout with lifetime-based aliasing (total ~322 MB) ----
  unsigned char* w = (unsigned char*)d_ws;
  const size_t MAT16 = (size_t)MTOT * DDC * 2;  // 64 MB
  size_t off = 0;
  uint16_t* R1 = (uint16_t*)(w + off); off += MAT16;
  uint16_t* R2 = (uint16_t*)(w + off); off += MAT16;
  uint16_t* R3 = (uint16_t*)(w + off); off += MAT16;
  uint16_t* R4 = (uint16_t*)(w + off); off += MAT16;
  uint16_t* R5 = (uint16_t*)(w + off); off += MAT16;  // max(Vm, Sc-chunk) = 64MB
  uint16_t* Wq = (uint16_t*)(w + off); off += 512 * 512 * 2;
  uint16_t* Wk = (uint16_t*)(w + off); off += 512 * 512 * 2;
  uint16_t* Wv = (uint16_t*)(w + off); off += 512 * 512 * 2;
  uint16_t* Wo = (uint16_t*)(w + off); off += 512 * 512 * 2;
  uint16_t* Gw = (uint16_t*)(w + off); off += 256 * 256 * 2;

  uint16_t* Xq  = R1; uint16_t* Vt  = R1;
  uint16_t* Xkv = R2; uint16_t* Ctx = R2;
  uint16_t* Qm  = R3; uint16_t* Mag = R3;
  uint16_t* Km  = R4;
  uint16_t* Vm  = R5; uint16_t* Sc  = R5;

  float* outR = (float*)d_out;
  float* outI = (float*)d_out + (long)MTOT * 256;

  // 1. packs
  pack_x<<<32768, 256, 0, stream>>>(q_in_r, q_in_i, Xq);
  pack_x<<<32768, 256, 0, stream>>>(kv_in_r, kv_in_i, Xkv);
  pack_w<<<256, 256, 0, stream>>>(q_wr, q_wi, Wq);
  pack_w<<<256, 256, 0, stream>>>(k_wr, k_wi, Wk);
  pack_w<<<256, 256, 0, stream>>>(v_wr, v_wi, Wv);
  pack_w<<<256, 256, 0, stream>>>(o_wr, o_wi, Wo);
  pack_gw<<<64, 256, 0, stream>>>(gate_w, Gw);

  // 2. projections (Q first frees R1 for Vt)
  gemm_bt<EP_PROJ><<<dim3(4, 512, 1), 512, 0, stream>>>(
      Xq, 512, 0, Wq, 512, 0, Qm, 512, 0, 512, q_br, q_bi, 1.f, nullptr, nullptr);
  gemm_bt<EP_PROJ><<<dim3(4, 512, 1), 512, 0, stream>>>(
      Xkv, 512, 0, Wk, 512, 0, Km, 512, 0, 512, k_br, k_bi, 1.f, nullptr, nullptr);
  gemm_bt<EP_PROJ><<<dim3(4, 512, 1), 512, 0, stream>>>(
      Xkv, 512, 0, Wv, 512, 0, Vm, 512, 0, 512, v_br, v_bi, 1.f, nullptr, nullptr);
  transpose_v<<<dim3(64, 16, 32), 256, 0, stream>>>(Vm, Vt);  // Vt overwrites Xq

  // 3. attention, chunked by HCHUNK heads (Sc chunk overwrites Vm region)
  for (int c = 0; c < NHEADS / HCHUNK; ++c) {
    const long ho = (long)c * HCHUNK;
    // S = Q K^T / 16  (fp16 out)
    gemm_bt<EP_F16Z><<<dim3(16, 16, HCHUNK), 512, 0, stream>>>(
        Qm + ho * TSEQ * DDC, 512, (long)TSEQ * DDC,
        Km + ho * TSEQ * DDC, 512, (long)TSEQ * DDC,
        Sc, TSEQ, (long)TSEQ * TSEQ, 512, nullptr, nullptr, 0.0625f, nullptr, nullptr);
    // softmax rows in place
    softmax_rows<<<HCHUNK * TSEQ, 256, 0, stream>>>(Sc);
    // ctx = P Vt^T
    gemm_bt<EP_F16Z><<<dim3(4, 16, HCHUNK), 512, 0, stream>>>(
        Sc, TSEQ, (long)TSEQ * TSEQ,
        Vt + ho * DDC * TSEQ, TSEQ, (long)DDC * TSEQ,
        Ctx + ho * TSEQ * DDC, 512, (long)TSEQ * DDC, 2048,
        nullptr, nullptr, 1.f, nullptr, nullptr);
  }

  // 4. out projection -> d_out (fp32, split r/i)
  gemm_bt<EP_OUT><<<dim3(4, 512, 1), 512, 0, stream>>>(
      Ctx, 512, 0, Wo, 512, 0, nullptr, 0, 0, 512, o_br, o_bi, 1.f, outR, outI);

  // 5. magnitude (Mag overwrites Qm region)
  mag_kernel<<<16384, 256, 0, stream>>>(outR, outI, Mag);

  // 6. gate gemm + sigmoid + in-place multiply of d_out
  gemm_bt<EP_GATE><<<dim3(2, 512, 1), 512, 0, stream>>>(
      Mag, 256, 0, Gw, 256, 0, nullptr, 0, 0, 256, gate_b, nullptr, 1.f, outR, outI);
}

// Round 6
// 1119.069 us; speedup vs baseline: 1.0454x; 1.0454x over previous
//
#include <hip/hip_runtime.h>
#include <hip/hip_bf16.h>
#include <hip/hip_fp16.h>
#include <stdint.h>

// ComplexAttention: B=4,H=8,T=2048,D=256
// R6: R4 geometry (BM=256; PV BM=128) + T4 counted-vmcnt pipeline:
//     STAGE(next) -> s_waitcnt vmcnt(L) -> s_barrier -> COMPUTE(cur)
//     -> s_barrier. Next tile's global_load_lds stay in flight across
//     both barriers (no vmcnt(0) drain in steady state).
//     Also: K+V projections merged into one N=1024 GEMM (Wk|Wv adjacent),
//     epilogue splits into Km/Vm so downstream + workspace unchanged.

#define TSEQ   2048
#define NHEADS 32
#define MTOT   65536   // 32*2048
#define DDC    512
#define HCHUNK 8

typedef float    f32x4  __attribute__((ext_vector_type(4)));
typedef _Float16 f16x8  __attribute__((ext_vector_type(8)));
typedef uint16_t u16x4  __attribute__((ext_vector_type(4)));
typedef uint16_t u16x8  __attribute__((ext_vector_type(8)));

__device__ __forceinline__ uint16_t f2h(float f) {
  _Float16 h = (_Float16)f;
  return __builtin_bit_cast(uint16_t, h);
}
__device__ __forceinline__ float h2f(uint16_t u) {
  return (float)__builtin_bit_cast(_Float16, u);
}

__device__ __forceinline__ void gld16(const void* g, void* l) {
  __builtin_amdgcn_global_load_lds(
      (const __attribute__((address_space(1))) uint32_t*)g,
      (__attribute__((address_space(3))) uint32_t*)l, 16, 0, 0);
}

enum { EP_F16Z = 0, EP_PROJ = 1, EP_OUT = 2, EP_GATE = 3 };

// C[M,N] = A[M,K] * B[N,K]^T  (A,B fp16; accum fp32)
// 512 thr = 8 waves (2M x 4N); tile BM x 256; BK=64.
// Per-wave output (BM/2) x 64 = MI x 4 mfma tiles, MI = BM/32.
// LDS: 2 buffers x (A[BM][64] + B[256][64]) fp16.
// Swizzle: LDS physical 16B-chunk p at row r holds global chunk p ^ (r&7);
// staging pre-swizzles the GLOBAL source (dest stays linear for
// global_load_lds), reads XOR the same key (row mod 8 == fr mod 8 always).
// EP_PROJ: blocks with tn>=512 write CV (V-matrix) at col-512 (merged KV).
template <int EP, int BM>
__global__ __launch_bounds__(512, (BM == 128) ? 4 : 2) void gemm_bt(
    const uint16_t* __restrict__ A, int lda, long zA,
    const uint16_t* __restrict__ B, int ldb, long zB,
    void* __restrict__ C, int ldc, long zC, uint16_t* __restrict__ CV,
    int K,
    const float* __restrict__ biasR, const float* __restrict__ biasI,
    float scale, float* __restrict__ outR, float* __restrict__ outI) {
  constexpr int MI    = BM / 32;        // acc row-tiles per wave
  constexpr int ASLAB = BM / 64;        // A staging slabs of 64 rows
  constexpr int ABUFE = BM * 64;        // A elems per buffer
  constexpr int BUFE  = (BM + 256) * 64;
  constexpr int NLOAD = ASLAB + 4;      // gld16 per thread per STAGE
  __shared__ uint16_t lds[2 * BUFE];

  const int tid  = threadIdx.x;
  const int wave = tid >> 6;            // 0..7
  const int lane = tid & 63;
  const int wr   = (wave >> 2) * (BM / 2);  // 2 M-warps
  const int wc   = (wave & 3) * 64;         // 4 N-warps

  // ---- XCD-aware swizzle (T1): all grids pow2 dims, nwg % 8 == 0.
  const int gx = gridDim.x, gy = gridDim.y;
  const int nwg = gx * gy * gridDim.z;
  const int lin = blockIdx.x + gx * (blockIdx.y + gy * blockIdx.z);
  const int cpx = nwg >> 3;
  const int swz = (lin & 7) * cpx + (lin >> 3);
  const int shx = __popc(gx - 1);
  const int shy = __popc(gy - 1);
  const int bx = swz & (gx - 1);
  const int by = (swz >> shx) & (gy - 1);
  const int bz = swz >> (shx + shy);

  const long tm = (long)by * BM;
  const long tn = (long)bx * 256;
  const uint16_t* Ab = A + (long)bz * zA;
  const uint16_t* Bb = B + (long)bz * zB;

  f32x4 acc[MI][4] = {};

  // staging: one wave-instruction covers 8 rows x 64 cols (1 KB):
  //   HW dest = base + lane*16 -> row = lane>>3, physical chunk = lane&7.
  //   Global source chunk = (lane&7) ^ (lane>>3)  (the pre-swizzle).
  const int arow   = wave * 8 + (lane >> 3);   // row within a 64-row slab
  const int schunk = (lane & 7) ^ (lane >> 3); // pre-swizzled source chunk

  const int fr   = lane & 15;   // m/n index within mfma tile
  const int quad = lane >> 4;   // 16B k-chunk within the 32-col half
  const int sw   = fr & 7;      // row&7 of every fragment row this lane reads
  const int ch0  = ((0 + quad) ^ sw) * 16;  // byte offset, ks=0
  const int ch1  = ((4 + quad) ^ sw) * 16;  // byte offset, ks=1

  const int nt = K >> 6;  // BK = 64

  auto STAGE = [&](int buf, int t) {
    const long k0 = (long)t * 64 + schunk * 8;
    uint16_t* base = lds + buf * BUFE;
#pragma unroll
    for (int s = 0; s < ASLAB; ++s)
      gld16(Ab + (tm + s * 64 + arow) * (long)lda + k0,
            base + (s * 64 + wave * 8) * 64);
#pragma unroll
    for (int s = 0; s < 4; ++s)
      gld16(Bb + (tn + s * 64 + arow) * (long)ldb + k0,
            base + ABUFE + (s * 64 + wave * 8) * 64);
  };

  auto COMPUTE = [&](int buf) {
    const char* Abase = (const char*)(lds + buf * BUFE);
    const char* Bbase = Abase + 2 * ABUFE;
#pragma unroll
    for (int ks = 0; ks < 2; ++ks) {
      const int co = ks ? ch1 : ch0;
      f16x8 bf[4];
#pragma unroll
      for (int j = 0; j < 4; ++j)
        bf[j] = *(const f16x8*)(Bbase + (wc + j * 16 + fr) * 128 + co);
#pragma unroll
      for (int i = 0; i < MI; ++i) {
        const f16x8 af = *(const f16x8*)(Abase + (wr + i * 16 + fr) * 128 + co);
#pragma unroll
        for (int j = 0; j < 4; ++j)
          acc[i][j] = __builtin_amdgcn_mfma_f32_16x16x32_f16(af, bf[j], acc[i][j], 0, 0, 0);
      }
    }
  };

  // T4 counted-vmcnt pipeline: next tile's NLOAD loads/thread stay in
  // flight across both barriers; only the last tile drains to 0.
  STAGE(0, 0);
  int cur = 0;
  for (int t = 0; t < nt; ++t) {
    if (t + 1 < nt) {
      STAGE(cur ^ 1, t + 1);
      if constexpr (NLOAD == 8)      asm volatile("s_waitcnt vmcnt(8)" ::: "memory");
      else if constexpr (NLOAD == 6) asm volatile("s_waitcnt vmcnt(6)" ::: "memory");
      else                           asm volatile("s_waitcnt vmcnt(0)" ::: "memory");
    } else {
      asm volatile("s_waitcnt vmcnt(0)" ::: "memory");
    }
    __builtin_amdgcn_s_barrier();            // publish buf cur (all waves)
    __builtin_amdgcn_sched_barrier(0);
    COMPUTE(cur);
    __builtin_amdgcn_sched_barrier(0);
    __builtin_amdgcn_s_barrier();            // all done reading buf cur
    __builtin_amdgcn_sched_barrier(0);
    cur ^= 1;
  }

  // ---- epilogues ----
  if constexpr (EP == EP_F16Z || EP == EP_PROJ) {
    // LDS repack: per-wave (BM/2)x64 fp16 region, XOR bits5-6 by (row>>2)&3
    // -> conflict-free (0 conflicts measured in R4); then 16B coalesced
    // global stores (full sectors, no write RMW).
    __syncthreads();
    char* wbase = (char*)lds + wave * (BM * 64);
    // EP_PROJ merged-KV split: V-half blocks (tn>=512) write CV at col-512.
    uint16_t* Cp;
    int coff = 0;
    if constexpr (EP == EP_PROJ) {
      const bool vhalf = (CV != nullptr) && (tn >= 512);
      Cp = vhalf ? CV : (uint16_t*)C;
      coff = vhalf ? 512 : 0;
    } else {
      Cp = (uint16_t*)C + (long)bz * zC;
    }
#pragma unroll
    for (int i = 0; i < MI; ++i) {
#pragma unroll
      for (int j = 0; j < 4; ++j) {
#pragma unroll
        for (int r = 0; r < 4; ++r) {
          const int row = i * 16 + quad * 4 + r;
          int byte = row * 128 + (j * 16 + fr) * 2;
          byte ^= ((row >> 2) & 3) << 5;
          float v = acc[i][j][r];
          if constexpr (EP == EP_PROJ) {
            const int col = (int)tn + wc + j * 16 + fr;
            v += biasR[col];               // prepacked full-width bias
          } else {
            v *= scale;
          }
          *(uint16_t*)(wbase + byte) = f2h(v);
        }
      }
    }
    asm volatile("s_waitcnt lgkmcnt(0)" ::: "memory");
    __builtin_amdgcn_sched_barrier(0);
#pragma unroll
    for (int it = 0; it < BM / 16; ++it) {
      const int row = it * 8 + (lane >> 3);
      const int c   = lane & 7;
      int byte = row * 128 + c * 16;
      byte ^= ((row >> 2) & 3) << 5;
      const u16x8 val = *(const u16x8*)(wbase + byte);
      const long grow = tm + wr + row;
      const int  gcol = (int)tn + wc + c * 8 - coff;
      *(u16x8*)(Cp + grow * (long)ldc + gcol) = val;
    }
  } else {
    // fp32 outputs: 16 lanes x 4B = 64B segments; direct store.
#pragma unroll
    for (int i = 0; i < MI; ++i) {
      const long row0 = tm + wr + i * 16 + quad * 4;
#pragma unroll
      for (int j = 0; j < 4; ++j) {
        const int col = (int)tn + wc + j * 16 + fr;
#pragma unroll
        for (int r = 0; r < 4; ++r) {
          float v = acc[i][j][r];
          const long rw = row0 + r;
          if constexpr (EP == EP_OUT) {
            if (col < 256) outR[rw * 256 + col]       = v + biasR[col];
            else           outI[rw * 256 + col - 256] = v + biasI[col - 256];
          } else {  // EP_GATE
            const float g = 1.0f / (1.0f + __expf(-(v + biasR[col])));
            const long o = rw * 256 + col;
            outR[o] *= g;
            outI[o] *= g;
          }
        }
      }
    }
  }
}

// x fp32 (r,i halves of 256) -> fp16 [m][512]
__global__ void pack_x(const float* __restrict__ xr, const float* __restrict__ xi,
                       uint16_t* __restrict__ out) {
  const long idx = (long)blockIdx.x * 256 + threadIdx.x;  // 4 elems each
  const long m  = idx >> 7;
  const int  c4 = (int)(idx & 127) << 2;
  const float* src = (c4 < 256) ? (xr + m * 256 + c4) : (xi + m * 256 + (c4 - 256));
  const float4 v = *(const float4*)src;
  u16x4 o = {f2h(v.x), f2h(v.y), f2h(v.z), f2h(v.w)};
  *(u16x4*)(out + m * 512 + c4) = o;
}

// Wc[512][512] = [[wr, -wi], [wi, wr]] fp16
__global__ void pack_w(const float* __restrict__ wr, const float* __restrict__ wi,
                       uint16_t* __restrict__ out) {
  const int idx = blockIdx.x * 256 + threadIdx.x;
  const int j  = idx >> 7;
  const int c4 = (idx & 127) << 2;
  const float* src;
  float sgn = 1.f;
  if (j < 256) {
    if (c4 < 256) src = wr + j * 256 + c4;
    else { src = wi + j * 256 + (c4 - 256); sgn = -1.f; }
  } else {
    if (c4 < 256) src = wi + (j - 256) * 256 + c4;
    else          src = wr + (j - 256) * 256 + (c4 - 256);
  }
  const float4 v = *(const float4*)src;
  u16x4 o = {f2h(sgn * v.x), f2h(sgn * v.y), f2h(sgn * v.z), f2h(sgn * v.w)};
  *(u16x4*)(out + (long)j * 512 + c4) = o;
}

__global__ void pack_gw(const float* __restrict__ w, uint16_t* __restrict__ out) {
  const int idx = blockIdx.x * 256 + threadIdx.x;
  const float4 v = *(const float4*)(w + (long)idx * 4);
  u16x4 o = {f2h(v.x), f2h(v.y), f2h(v.z), f2h(v.w)};
  *(u16x4*)(out + (long)idx * 4) = o;
}

// prepacked biases: bq[512] = q_br||q_bi ; bkv[1024] = k_br||k_bi||v_br||v_bi
__global__ void pack_bias(const float* __restrict__ qbr, const float* __restrict__ qbi,
                          const float* __restrict__ kbr, const float* __restrict__ kbi,
                          const float* __restrict__ vbr, const float* __restrict__ vbi,
                          float* __restrict__ bq, float* __restrict__ bkv) {
  const int i = blockIdx.x * 256 + threadIdx.x;  // grid 6*256 = 1536
  if (i < 256)       bq[i] = qbr[i];
  else if (i < 512)  bq[i] = qbi[i - 256];
  else if (i < 768)  bkv[i - 512] = kbr[i - 512];
  else if (i < 1024) bkv[i - 512] = kbi[i - 768];
  else if (i < 1280) bkv[i - 512] = vbr[i - 1024];
  else               bkv[i - 512] = vbi[i - 1280];
}

// per head: V[2048][512] -> Vt[512][2048]
__global__ void transpose_v(const uint16_t* __restrict__ V, uint16_t* __restrict__ Vt) {
  __shared__ uint16_t t[32][33];
  const int h = blockIdx.z;
  const uint16_t* Vh = V + (long)h * TSEQ * DDC;
  uint16_t* Vth = Vt + (long)h * DDC * TSEQ;
  const int t0 = blockIdx.x * 32;
  const int n0 = blockIdx.y * 32;
  const int lx = threadIdx.x & 31, ly = threadIdx.x >> 5;  // 32x8
#pragma unroll
  for (int yy = ly; yy < 32; yy += 8)
    t[yy][lx] = Vh[(long)(t0 + yy) * DDC + n0 + lx];
  __syncthreads();
#pragma unroll
  for (int yy = ly; yy < 32; yy += 8)
    Vth[(long)(n0 + yy) * TSEQ + t0 + lx] = t[lx][yy];
}

// one block per score row: 2048 fp16 in, softmax, fp16 out (in place)
__global__ __launch_bounds__(256) void softmax_rows(uint16_t* __restrict__ S) {
  const long row = blockIdx.x;
  uint16_t* p = S + row * 2048;
  const int tid = threadIdx.x;
  u16x8 raw = ((const u16x8*)p)[tid];
  float v[8];
#pragma unroll
  for (int j = 0; j < 8; ++j) v[j] = h2f(raw[j]);
  float m = v[0];
#pragma unroll
  for (int j = 1; j < 8; ++j) m = fmaxf(m, v[j]);
#pragma unroll
  for (int off = 32; off >= 1; off >>= 1) m = fmaxf(m, __shfl_xor(m, off));
  __shared__ float red[8];
  const int wave = tid >> 6, lane = tid & 63;
  if (lane == 0) red[wave] = m;
  __syncthreads();
  m = fmaxf(fmaxf(red[0], red[1]), fmaxf(red[2], red[3]));
  float s = 0.f;
#pragma unroll
  for (int j = 0; j < 8; ++j) { v[j] = __expf(v[j] - m); s += v[j]; }
#pragma unroll
  for (int off = 32; off >= 1; off >>= 1) s += __shfl_xor(s, off);
  if (lane == 0) red[4 + wave] = s;
  __syncthreads();
  s = red[4] + red[5] + red[6] + red[7];
  const float inv = 1.0f / s;
  u16x8 o;
#pragma unroll
  for (int j = 0; j < 8; ++j) o[j] = f2h(v[j] * inv);
  ((u16x8*)p)[tid] = o;
}

__global__ void mag_kernel(const float* __restrict__ R, const float* __restrict__ I,
                           uint16_t* __restrict__ mag) {
  const long i = ((long)blockIdx.x * 256 + threadIdx.x) * 4;
  const float4 r  = *(const float4*)(R + i);
  const float4 im = *(const float4*)(I + i);
  u16x4 o = {f2h(sqrtf(r.x * r.x + im.x * im.x + 1e-8f)),
             f2h(sqrtf(r.y * r.y + im.y * im.y + 1e-8f)),
             f2h(sqrtf(r.z * r.z + im.z * im.z + 1e-8f)),
             f2h(sqrtf(r.w * r.w + im.w * im.w + 1e-8f))};
  *(u16x4*)(mag + i) = o;
}

extern "C" void kernel_launch(void* const* d_in, const int* in_sizes, int n_in,
                              void* d_out, int out_size, void* d_ws, size_t ws_size,
                              hipStream_t stream) {
  const float* q_in_r  = (const float*)d_in[0];
  const float* q_in_i  = (const float*)d_in[1];
  const float* kv_in_r = (const float*)d_in[2];
  const float* kv_in_i = (const float*)d_in[3];
  const float* q_wr = (const float*)d_in[4];
  const float* q_wi = (const float*)d_in[5];
  const float* q_br = (const float*)d_in[6];
  const float* q_bi = (const float*)d_in[7];
  const float* k_wr = (const float*)d_in[8];
  const float* k_wi = (const float*)d_in[9];
  const float* k_br = (const float*)d_in[10];
  const float* k_bi = (const float*)d_in[11];
  const float* v_wr = (const float*)d_in[12];
  const float* v_wi = (const float*)d_in[13];
  const float* v_br = (const float*)d_in[14];
  const float* v_bi = (const float*)d_in[15];
  const float* o_wr = (const float*)d_in[16];
  const float* o_wi = (const float*)d_in[17];
  const float* o_br = (const float*)d_in[18];
  const float* o_bi = (const float*)d_in[19];
  const float* gate_w = (const float*)d_in[20];
  const float* gate_b = (const float*)d_in[21];

  // ---- workspace layout with lifetime-based aliasing (total ~322 MB) ----
  unsigned char* w = (unsigned char*)d_ws;
  const size_t MAT16 = (size_t)MTOT * DDC * 2;  // 64 MB
  size_t off = 0;
  uint16_t* R1 = (uint16_t*)(w + off); off += MAT16;
  uint16_t* R2 = (uint16_t*)(w + off); off += MAT16;
  uint16_t* R3 = (uint16_t*)(w + off); off += MAT16;
  uint16_t* R4 = (uint16_t*)(w + off); off += MAT16;
  uint16_t* R5 = (uint16_t*)(w + off); off += MAT16;  // max(Vm, Sc-chunk) = 64MB
  uint16_t* Wq = (uint16_t*)(w + off); off += 512 * 512 * 2;
  uint16_t* Wk = (uint16_t*)(w + off); off += 512 * 512 * 2;
  uint16_t* Wv = (uint16_t*)(w + off); off += 512 * 512 * 2;  // = Wk + 512*512
  uint16_t* Wo = (uint16_t*)(w + off); off += 512 * 512 * 2;
  uint16_t* Gw = (uint16_t*)(w + off); off += 256 * 256 * 2;
  float*    Bq  = (float*)(w + off);   off += 512 * 4;
  float*    Bkv = (float*)(w + off);   off += 1024 * 4;

  uint16_t* Xq  = R1; uint16_t* Vt  = R1;
  uint16_t* Xkv = R2; uint16_t* Ctx = R2;
  uint16_t* Qm  = R3; uint16_t* Mag = R3;
  uint16_t* Km  = R4;
  uint16_t* Vm  = R5; uint16_t* Sc  = R5;

  float* outR = (float*)d_out;
  float* outI = (float*)d_out + (long)MTOT * 256;

  // 1. packs
  pack_x<<<32768, 256, 0, stream>>>(q_in_r, q_in_i, Xq);
  pack_x<<<32768, 256, 0, stream>>>(kv_in_r, kv_in_i, Xkv);
  pack_w<<<256, 256, 0, stream>>>(q_wr, q_wi, Wq);
  pack_w<<<256, 256, 0, stream>>>(k_wr, k_wi, Wk);
  pack_w<<<256, 256, 0, stream>>>(v_wr, v_wi, Wv);
  pack_w<<<256, 256, 0, stream>>>(o_wr, o_wi, Wo);
  pack_gw<<<64, 256, 0, stream>>>(gate_w, Gw);
  pack_bias<<<6, 256, 0, stream>>>(q_br, q_bi, k_br, k_bi, v_br, v_bi, Bq, Bkv);

  // 2. projections (Q first frees R1 for Vt); K+V merged (N=1024, B=[Wk;Wv])
  gemm_bt<EP_PROJ, 256><<<dim3(2, 256, 1), 512, 0, stream>>>(
      Xq, 512, 0, Wq, 512, 0, Qm, 512, 0, nullptr, 512, Bq, nullptr, 1.f,
      nullptr, nullptr);
  gemm_bt<EP_PROJ, 256><<<dim3(4, 256, 1), 512, 0, stream>>>(
      Xkv, 512, 0, Wk, 512, 0, Km, 512, 0, Vm, 512, Bkv, nullptr, 1.f,
      nullptr, nullptr);
  transpose_v<<<dim3(64, 16, 32), 256, 0, stream>>>(Vm, Vt);  // Vt overwrites Xq

  // 3. attention, chunked by HCHUNK heads (Sc chunk overwrites Vm region)
  for (int c = 0; c < NHEADS / HCHUNK; ++c) {
    const long ho = (long)c * HCHUNK;
    // S = Q K^T / 16  (fp16 out)
    gemm_bt<EP_F16Z, 256><<<dim3(8, 8, HCHUNK), 512, 0, stream>>>(
        Qm + ho * TSEQ * DDC, 512, (long)TSEQ * DDC,
        Km + ho * TSEQ * DDC, 512, (long)TSEQ * DDC,
        Sc, TSEQ, (long)TSEQ * TSEQ, nullptr, 512,
        nullptr, nullptr, 0.0625f, nullptr, nullptr);
    // softmax rows in place
    softmax_rows<<<HCHUNK * TSEQ, 256, 0, stream>>>(Sc);
    // ctx = P Vt^T   (BM=128 -> 256 blocks)
    gemm_bt<EP_F16Z, 128><<<dim3(2, 16, HCHUNK), 512, 0, stream>>>(
        Sc, TSEQ, (long)TSEQ * TSEQ,
        Vt + ho * DDC * TSEQ, TSEQ, (long)DDC * TSEQ,
        Ctx + ho * TSEQ * DDC, 512, (long)TSEQ * DDC, nullptr, 2048,
        nullptr, nullptr, 1.f, nullptr, nullptr);
  }

  // 4. out projection -> d_out (fp32, split r/i)
  gemm_bt<EP_OUT, 256><<<dim3(2, 256, 1), 512, 0, stream>>>(
      Ctx, 512, 0, Wo, 512, 0, nullptr, 0, 0, nullptr, 512,
      o_br, o_bi, 1.f, outR, outI);

  // 5. magnitude (Mag overwrites Qm region)
  mag_kernel<<<16384, 256, 0, stream>>>(outR, outI, Mag);

  // 6. gate gemm + sigmoid + in-place multiply of d_out
  gemm_bt<EP_GATE, 256><<<dim3(1, 256, 1), 512, 0, stream>>>(
      Mag, 256, 0, Gw, 256, 0, nullptr, 0, 0, nullptr, 256,
      gate_b, nullptr, 1.f, outR, outI);
}